// Round 4
// baseline (389.035 us; speedup 1.0000x reference)
//
#include <hip/hip_runtime.h>
#include <hip/hip_bf16.h>

#define B_ 4096
#define T_ 4
#define D_ 1024
#define E_ 4

typedef unsigned short ushort_t;
typedef float f32x16 __attribute__((ext_vector_type(16)));
typedef short bf16x8 __attribute__((ext_vector_type(8)));

__device__ __forceinline__ unsigned short f2bf(float f) {
    unsigned int u = __float_as_uint(f);
    u += 0x7FFF + ((u >> 16) & 1);   // round-to-nearest-even
    return (unsigned short)(u >> 16);
}
__device__ __forceinline__ float bf2f(unsigned short u) {
    return __uint_as_float(((unsigned int)u) << 16);
}

#define GLOBAL_LOAD_LDS16(gp, lp)                                                        \
    __builtin_amdgcn_global_load_lds((const __attribute__((address_space(1))) void*)(gp),\
                                     (__attribute__((address_space(3))) void*)(lp),      \
                                     16, 0, 0)

// XOR-swizzled LDS slot map (16B slots, 4 slots per 32-elem row):
//   slot(row, kq) = row*4 + (kq ^ ((row>>1)&3))     -> elem offset = slot*8
// staging inverse: slot q holds (row = q>>2, kq = (q&3) ^ ((q>>3)&3))
// => 8 consecutive rows sweep all 32 banks: conflict-free ds_read_b128.
#define LSLOT_E(row, kq) (((((row) << 2) + ((kq) ^ (((row) >> 1) & 3)))) << 3)
#define KQOF(q) ((((q) & 3) ^ (((q) >> 3) & 3)) * 8)

// Fused prep: z<16 -> W1/W2 transpose+cvt; z>=16 -> x [B,T,D] f32 -> Hbf [T,B,D] bf16
__global__ __launch_bounds__(256) void k_prep(const float* __restrict__ x,
                                              const float* __restrict__ W1,
                                              const float* __restrict__ W2,
                                              ushort_t* __restrict__ hbf,
                                              ushort_t* __restrict__ W1t,
                                              ushort_t* __restrict__ W2t) {
    const int z = blockIdx.z;
    const int tid = threadIdx.x;
    if (z >= 16) {
        const int blk = (z - 16) * 1024 + blockIdx.y * 32 + blockIdx.x;
        const int idx = (blk * 256 + tid) * 4;
        const int d = idx & (D_ - 1);
        const int t = (idx >> 10) & 3;
        const int b = idx >> 12;
        const float4 v = *(const float4*)(x + idx);
        ushort4 o = { f2bf(v.x), f2bf(v.y), f2bf(v.z), f2bf(v.w) };
        *(ushort4*)(hbf + (size_t)t * B_ * D_ + (size_t)b * D_ + d) = o;
        return;
    }
    __shared__ float tile[32][33];
    const float* src = (z < 8) ? (W1 + (size_t)z * D_ * D_) : (W2 + (size_t)(z - 8) * D_ * D_);
    ushort_t* dst = (z < 8) ? (W1t + (size_t)z * D_ * D_) : (W2t + (size_t)(z - 8) * D_ * D_);
    const int o0 = blockIdx.x * 32, d0 = blockIdx.y * 32;
    const int tx = tid & 31, ty = tid >> 5;  // 32 x 8
#pragma unroll
    for (int j = 0; j < 4; ++j)
        tile[ty + 8 * j][tx] = src[(size_t)(d0 + ty + 8 * j) * D_ + o0 + tx];
    __syncthreads();
#pragma unroll
    for (int j = 0; j < 4; ++j)
        dst[(size_t)(o0 + ty + 8 * j) * D_ + d0 + tx] = f2bf(tile[tx][ty + 8 * j]);
}

// C[4096,1024] = relu(A * Bt^T + bias) [* scale], batched over tasks.
// 256x128 block tile, 512 thr = 8 waves of 64x64 (2x2 frags of 32x32x16 MFMA),
// BK=32 double-buffered (48 KB), XOR-swizzled LDS (conflict-free b128 reads).
template <bool OUT_BF16>
__global__ __launch_bounds__(512, 4) void k_gemm_bt(
    const ushort_t* __restrict__ A,
    const ushort_t* __restrict__ Bt,
    const float* __restrict__ bias,   // [T, 1024]
    void* __restrict__ out,           // [T, 4096, 1024]
    const float* __restrict__ inte)   // [T, E] or null
{
    // XCD = f%8 = 2t + (m&1): each XCD's L2 holds ONE task's Bt (2 MB)
    const int f = blockIdx.x;           // 0..511
    const int xcd = f & 7;
    const int t = xcd >> 1;
    const int m_blk = ((f >> 6) << 1) | (xcd & 1);  // 0..15
    const int n_blk = (f >> 3) & 7;                 // 0..7
    const int m0 = m_blk * 256, n0 = n_blk * 128;

    const ushort_t* Ap = A + (size_t)t * B_ * D_;
    const ushort_t* Bp = Bt + (size_t)t * D_ * D_;
    const float* bp = bias + t * D_;

    __shared__ __align__(16) ushort_t As[2][256 * 32];   // 16 KB x2
    __shared__ __align__(16) ushort_t Bs[2][128 * 32];   //  8 KB x2

    const int tid = threadIdx.x;
    const int lane = tid & 63, wid = tid >> 6;           // 8 waves
    const int l31 = lane & 31, lh = lane >> 5;
    const int wm = (wid & 3) * 64, wn = (wid >> 2) * 64; // 4x2 wave grid

    f32x16 acc[2][2] = {};

    // staging: A = 1024 slots (2 insts/thread), B = 512 slots (1 inst)
    const int qa0 = wid * 64 + lane;        // 0..511
    const int qa1 = qa0 + 512;              // 512..1023
    const int qb  = qa0;
    const ushort_t* ga0 = Ap + (size_t)(m0 + (qa0 >> 2)) * D_ + KQOF(qa0);
    const ushort_t* ga1 = Ap + (size_t)(m0 + (qa1 >> 2)) * D_ + KQOF(qa1);
    const ushort_t* gb  = Bp + (size_t)(n0 + (qb  >> 2)) * D_ + KQOF(qb);

#define STAGE(k0, s)                                              \
    do {                                                          \
        GLOBAL_LOAD_LDS16(ga0 + (k0), As[s] + wid * 512);         \
        GLOBAL_LOAD_LDS16(ga1 + (k0), As[s] + 4096 + wid * 512);  \
        GLOBAL_LOAD_LDS16(gb  + (k0), Bs[s] + wid * 512);         \
    } while (0)

    STAGE(0, 0);
    int s = 0;
    for (int k0 = 0; k0 < D_; k0 += 32, s ^= 1) {
        __syncthreads();                    // drains buf-s loads
        if (k0 + 32 < D_) STAGE(k0 + 32, s ^ 1);  // flies during compute below
        bf16x8 af[2][2], bfv[2][2];
#pragma unroll
        for (int mi = 0; mi < 2; ++mi)
#pragma unroll
            for (int ks = 0; ks < 2; ++ks)
                af[mi][ks] = *(const bf16x8*)(As[s] + LSLOT_E(wm + mi * 32 + l31, ks * 2 + lh));
#pragma unroll
        for (int ni = 0; ni < 2; ++ni)
#pragma unroll
            for (int ks = 0; ks < 2; ++ks)
                bfv[ni][ks] = *(const bf16x8*)(Bs[s] + LSLOT_E(wn + ni * 32 + l31, ks * 2 + lh));
#pragma unroll
        for (int ks = 0; ks < 2; ++ks)
#pragma unroll
            for (int mi = 0; mi < 2; ++mi)
#pragma unroll
                for (int ni = 0; ni < 2; ++ni)
                    acc[mi][ni] = __builtin_amdgcn_mfma_f32_32x32x16_bf16(
                        af[mi][ks], bfv[ni][ks], acc[mi][ni], 0, 0, 0);
    }
#undef STAGE

    float scale = 1.0f;
    if (inte) {
        const float* ip = inte + t * E_;
        scale = ip[0] + ip[1] + ip[2] + ip[3];
    }
    // C/D 32x32: col = lane&31, row = (reg&3) + 8*(reg>>2) + 4*(lane>>5)
#pragma unroll
    for (int mi = 0; mi < 2; ++mi) {
#pragma unroll
        for (int ni = 0; ni < 2; ++ni) {
            const int gcol = n0 + wn + ni * 32 + l31;
            const float bv = bp[gcol];
#pragma unroll
            for (int reg = 0; reg < 16; ++reg) {
                const int grow = m0 + wm + mi * 32 + (reg & 3) + 8 * (reg >> 2) + 4 * lh;
                float v = acc[mi][ni][reg] + bv;
                v = fmaxf(v, 0.0f) * scale;
                const size_t off = (size_t)t * B_ * D_ + (size_t)grow * D_ + gcol;
                if (OUT_BF16) ((ushort_t*)out)[off] = f2bf(v);
                else          ((float*)out)[off] = v;
            }
        }
    }
}

// gate + combine: one block per batch row b
template <bool FINAL, bool TEO_BF16>
__global__ __launch_bounds__(256) void k_gate_combine(
    const void* __restrict__ teo_v, // [T, B, D] f32 or bf16
    const float* __restrict__ Wg,   // [D, T] f32
    const float* __restrict__ bg,   // [T] f32
    void* __restrict__ out)         // FINAL: f32 [B,T,D]; else bf16 [T,B,D]
{
    const int b = blockIdx.x;
    const int tid = threadIdx.x;
    const int d0 = tid * 4;

    float4 tv[4];
#pragma unroll
    for (int t = 0; t < 4; ++t) {
        if (TEO_BF16) {
            const ushort4 u = *(const ushort4*)((const ushort_t*)teo_v +
                                 (size_t)t * B_ * D_ + (size_t)b * D_ + d0);
            tv[t] = { bf2f(u.x), bf2f(u.y), bf2f(u.z), bf2f(u.w) };
        } else {
            tv[t] = *(const float4*)((const float*)teo_v +
                                 (size_t)t * B_ * D_ + (size_t)b * D_ + d0);
        }
    }
    float4 wg[4];
#pragma unroll
    for (int i = 0; i < 4; ++i)
        wg[i] = *(const float4*)(Wg + (size_t)(d0 + i) * 4);

    float p[16];
#pragma unroll
    for (int t = 0; t < 4; ++t) {
        const float* tvp = (const float*)&tv[t];
#pragma unroll
        for (int k = 0; k < 4; ++k) {
            p[t * 4 + k] = tvp[0] * ((const float*)&wg[0])[k]
                         + tvp[1] * ((const float*)&wg[1])[k]
                         + tvp[2] * ((const float*)&wg[2])[k]
                         + tvp[3] * ((const float*)&wg[3])[k];
        }
    }
#pragma unroll
    for (int i = 0; i < 16; ++i) {
        float v = p[i];
        v += __shfl_xor(v, 1, 64);
        v += __shfl_xor(v, 2, 64);
        v += __shfl_xor(v, 4, 64);
        v += __shfl_xor(v, 8, 64);
        p[i] = v;
    }
    __shared__ float red[16][16];
    __shared__ float fin[16];
    const int grp = tid >> 4;
    if ((tid & 15) == 0) {
#pragma unroll
        for (int i = 0; i < 16; ++i) red[grp][i] = p[i];
    }
    __syncthreads();
    if (tid < 16) {
        float v = 0.0f;
#pragma unroll
        for (int g = 0; g < 16; ++g) v += red[g][tid];
        fin[tid] = v;
    }
    __syncthreads();

    float g[4][4];
#pragma unroll
    for (int t = 0; t < 4; ++t) {
        float lg[4];
#pragma unroll
        for (int k = 0; k < 4; ++k)
            lg[k] = fin[t * 4 + k] + bg[k];
        float mx = fmaxf(fmaxf(lg[0], lg[1]), fmaxf(lg[2], lg[3]));
        float e0 = __expf(lg[0] - mx), e1 = __expf(lg[1] - mx);
        float e2 = __expf(lg[2] - mx), e3 = __expf(lg[3] - mx);
        float inv = 1.0f / (e0 + e1 + e2 + e3);
        g[t][0] = e0 * inv; g[t][1] = e1 * inv; g[t][2] = e2 * inv; g[t][3] = e3 * inv;
    }
#pragma unroll
    for (int t = 0; t < 4; ++t) {
        float o[4];
#pragma unroll
        for (int i = 0; i < 4; ++i) {
            o[i] = g[t][0] * ((const float*)&tv[0])[i]
                 + g[t][1] * ((const float*)&tv[1])[i]
                 + g[t][2] * ((const float*)&tv[2])[i]
                 + g[t][3] * ((const float*)&tv[3])[i]
                 + ((const float*)&tv[t])[i];
        }
        if (FINAL) {
            float4 ov = { o[0], o[1], o[2], o[3] };
            *(float4*)((float*)out + (size_t)b * T_ * D_ + (size_t)t * D_ + d0) = ov;
        } else {
            ushort4 ov = { f2bf(o[0]), f2bf(o[1]), f2bf(o[2]), f2bf(o[3]) };
            *(ushort4*)((ushort_t*)out + (size_t)t * B_ * D_ + (size_t)b * D_ + d0) = ov;
        }
    }
}

extern "C" void kernel_launch(void* const* d_in, const int* in_sizes, int n_in,
                              void* d_out, int out_size, void* d_ws, size_t ws_size,
                              hipStream_t stream) {
    const float* x    = (const float*)d_in[0];
    const float* W1   = (const float*)d_in[1];
    const float* b1   = (const float*)d_in[2];
    const float* W2   = (const float*)d_in[3];
    const float* b2   = (const float*)d_in[4];
    const float* inte = (const float*)d_in[5];
    const float* Wg   = (const float*)d_in[6];
    const float* bg   = (const float*)d_in[7];

    char* ws = (char*)d_ws;
    // ws layout (bytes): W1t 32M | W2t 32M | Hbf 32M | T1bf 32M | Teo 64M = 192 MiB
    ushort_t* W1t  = (ushort_t*)(ws);
    ushort_t* W2t  = (ushort_t*)(ws + 33554432);
    ushort_t* Hbf  = (ushort_t*)(ws + 67108864);
    ushort_t* T1bf = (ushort_t*)(ws + 100663296);
    void*     Teo  = (void*)    (ws + 134217728);  // L0: bf16, L1: f32

    k_prep<<<dim3(32, 32, 32), 256, 0, stream>>>(x, W1, W2, Hbf, W1t, W2t);

    for (int l = 0; l < 2; ++l) {
        const size_t wOff = (size_t)l * T_ * D_ * D_;
        k_gemm_bt<true><<<dim3(512), 512, 0, stream>>>(Hbf, W1t + wOff, b1 + l * T_ * D_,
                                                       (void*)T1bf, nullptr);
        if (l == 0) {
            k_gemm_bt<true ><<<dim3(512), 512, 0, stream>>>(T1bf, W2t + wOff, b2 + l * T_ * D_,
                                                            Teo, inte + l * T_ * E_);
            k_gate_combine<false, true ><<<dim3(B_), 256, 0, stream>>>(
                Teo, Wg + l * D_ * T_, bg + l * T_, (void*)Hbf);
        } else {
            k_gemm_bt<false><<<dim3(512), 512, 0, stream>>>(T1bf, W2t + wOff, b2 + l * T_ * D_,
                                                            Teo, inte + l * T_ * E_);
            k_gate_combine<true , false><<<dim3(B_), 256, 0, stream>>>(
                Teo, Wg + l * D_ * T_, bg + l * T_, (void*)d_out);
        }
    }
}